// Round 8
// baseline (204.197 us; speedup 1.0000x reference)
//
#include <hip/hip_runtime.h>

#define NB 512
#define NN 256
#define EPG 8192
#define FINC 128

typedef float f32x4 __attribute__((ext_vector_type(4)));
typedef short s16x8 __attribute__((ext_vector_type(8)));

__device__ __forceinline__ float bf2f(unsigned short u) {
  union { unsigned int i; float f; } x; x.i = ((unsigned int)u) << 16; return x.f;
}
__device__ __forceinline__ unsigned short f2bf(float f) {
  union { float f; unsigned int i; } x; x.f = f;
  unsigned int r = x.i + 0x7fffu + ((x.i >> 16) & 1u);
  return (unsigned short)(r >> 16);
}
// exact for small non-negative integers
__device__ __forceinline__ short ftrunc_bf(float f) {
  union { float f; unsigned int i; } x; x.f = f;
  return (short)(x.i >> 16);
}

struct Params {
  const void* x; const void* ei;
  const void *wl1, *bl1, *wr1, *br1, *wro1, *wp, *bp;
  const void *wr2, *br2, *wro2, *wl2, *bl2, *wl3, *bl3;
  float* out; float* ws;
};

__device__ __forceinline__ bool detect_bf16(const void* p) {
  const unsigned short* pw = (const unsigned short*)p;
  int sane = 0;
  for (int i = 0; i < 64; ++i) {
    unsigned e = (pw[i] >> 7) & 0xFFu;
    sane += (e > 96u && e < 132u) ? 1 : 0;
  }
  return sane >= 56;
}
__device__ __forceinline__ bool detect_i64(const void* p) {
  const int* pi = (const int*)p + EPG;
  int ok = 0;
  for (int i = 0; i < 32; ++i) ok += (pi[i] >= 256 && pi[i] < 512) ? 1 : 0;
  return ok < 24;
}
__device__ __forceinline__ float ldf(const void* p, int i, bool bf) {
  return bf ? bf2f(((const unsigned short*)p)[i]) : ((const float*)p)[i];
}

// ---- LDS (81920 B total => 2 blocks/CU) ----
// A [0,33792):     adj u4 [256 rows][132 B]; after P5: tail bufs + FG + jobs
// B [33792,50688): h0T bf16 [32][264] (P1->Pz1); yTl [16][264] (Pz2->4a);
//                  h1Th [32][264] (4b->P6)
// C [50688,67584): W1T bf16 [32][136] (P0->P1); zT [32][264] (Pz1->4a);
//                  sTh/sTl [16][264] x2 (4b->P6)
// D [67584,76032): wrelTh/l + wrootT [32][40] + blin1f (P0->Pz1);
//                  yTh [16][264] (Pz2->4a); taT [16][264] (P5->P6)
// E [76032,81920): wpoolTh/l, m1Th/l, m2Th [16][36]; bMf; brel1h  (persistent)
#define SMEM_TOTAL 81920

__global__ __launch_bounds__(1024, 8) void mincut_main(Params P) {
  extern __shared__ char smem[];
  const int t = threadIdx.x;
  const int b = blockIdx.x;

  const bool BF  = detect_bf16(P.wr1);
  const bool I64 = detect_i64(P.ei);

  // A tail
  float* pbuf   = (float*)(smem + 0);
  float* oadjb  = (float*)(smem + 2048);
  float* ssb    = (float*)(smem + 3072);
  float* qbuf   = (float*)(smem + 4096);
  float* ddb    = (float*)(smem + 6144);
  float* h2b    = (float*)(smem + 6208);
  float* rb     = (float*)(smem + 8256);
  float* yb     = (float*)(smem + 8384);
  float* lgb    = (float*)(smem + 8512);
  float* scr    = (float*)(smem + 8704);    // 64 f
  float* rel2f  = (float*)(smem + 9216);
  float* root2f = (float*)(smem + 13312);
  float* lin2f  = (float*)(smem + 17408);
  float* lin3f  = (float*)(smem + 21504);
  float* brel2f = (float*)(smem + 22784);
  float* blin2f = (float*)(smem + 22912);
  float* blin3f = (float*)(smem + 23040);
  float* pbufH  = (float*)(smem + 24576);
  float* pbufL  = (float*)(smem + 26624);
  float* oadjH  = (float*)(smem + 28672);
  float* oadjL  = (float*)(smem + 29696);
  float* ssA    = (float*)(smem + 30720);
  float* ssX    = (float*)(smem + 31744);
  // B
  unsigned short* h0T  = (unsigned short*)(smem + 33792);
  unsigned short* yTl  = (unsigned short*)(smem + 33792);
  unsigned short* h1Th = (unsigned short*)(smem + 33792);
  // C
  unsigned short* w1t  = (unsigned short*)(smem + 50688);
  unsigned short* zT   = (unsigned short*)(smem + 50688);
  unsigned short* sTh  = (unsigned short*)(smem + 50688);
  unsigned short* sTl  = (unsigned short*)(smem + 59136);
  // D
  unsigned short* wrelTh = (unsigned short*)(smem + 67584);
  unsigned short* wrelTl = (unsigned short*)(smem + 70144);
  unsigned short* wrootT = (unsigned short*)(smem + 72704);
  float* blin1f = (float*)(smem + 75264);   // 32 f (dead after P1)
  unsigned short* yTh = (unsigned short*)(smem + 67584);
  unsigned short* taT = (unsigned short*)(smem + 67584);
  // E
  unsigned short* wpoolTh = (unsigned short*)(smem + 76032); // [16][36]
  unsigned short* wpoolTl = (unsigned short*)(smem + 77184);
  unsigned short* m1Th    = (unsigned short*)(smem + 78336);
  unsigned short* m1Tl    = (unsigned short*)(smem + 79488);
  unsigned short* m2Th    = (unsigned short*)(smem + 80640);
  float*          bMf     = (float*)(smem + 81792);          // 16 f
  unsigned short* brel1h  = (unsigned short*)(smem + 81856); // 32 bf16

  const int wv = t >> 6, lane = t & 63;
  const int lm = lane & 15, quad = lane >> 4;
  const int mbase = wv * 16;

  // ---- edge prefetch (latency hides under P0/P1) ----
  int eu[8], ev[8];
  if (I64) {
    const uint4* s4 = (const uint4*)((const long long*)P.ei + (size_t)b * EPG) + t * 4;
    const uint4* d4 = (const uint4*)((const long long*)P.ei + (size_t)NB * EPG + (size_t)b * EPG) + t * 4;
    #pragma unroll
    for (int i = 0; i < 4; ++i) {
      uint4 a = s4[i], c = d4[i];
      eu[2 * i] = a.x & 255; eu[2 * i + 1] = a.z & 255;
      ev[2 * i] = c.x & 255; ev[2 * i + 1] = c.z & 255;
    }
  } else {
    const uint4* s4 = (const uint4*)((const int*)P.ei + (size_t)b * EPG) + t * 2;
    const uint4* d4 = (const uint4*)((const int*)P.ei + (size_t)NB * EPG + (size_t)b * EPG) + t * 2;
    #pragma unroll
    for (int i = 0; i < 2; ++i) {
      uint4 a = s4[i], c = d4[i];
      eu[4 * i] = a.x & 255; eu[4 * i + 1] = a.y & 255; eu[4 * i + 2] = a.z & 255; eu[4 * i + 3] = a.w & 255;
      ev[4 * i] = c.x & 255; ev[4 * i + 1] = c.y & 255; ev[4 * i + 2] = c.z & 255; ev[4 * i + 3] = c.w & 255;
    }
  }

  // ---- P0: zero adj (u4) + stage W1T, wrelT h/l, wrootT, wpoolT h/l, biases ----
  {
    uint4 z = {0u, 0u, 0u, 0u};
    for (int i = t; i < 2112; i += 1024) ((uint4*)smem)[i] = z;
  }
  for (int e = t; e < 4096; e += 1024) {
    int k = e >> 5, c = e & 31;
    w1t[c * 136 + k] = f2bf(ldf(P.wl1, e, BF));
  }
  {
    int k = t >> 5, c = t & 31;
    float wr = ldf(P.wr1, t, BF);
    unsigned short hi = f2bf(wr);
    wrelTh[c * 40 + k] = hi;
    wrelTl[c * 40 + k] = f2bf(wr - bf2f(hi));
    wrootT[c * 40 + k] = f2bf(ldf(P.wro1, t, BF));
  }
  if (t < 512) {
    int m = t >> 4, c = t & 15;
    float w = ldf(P.wp, t, BF);
    unsigned short hi = f2bf(w);
    wpoolTh[c * 36 + m] = hi;
    wpoolTl[c * 36 + m] = f2bf(w - bf2f(hi));
  }
  if (t < 32) { blin1f[t] = ldf(P.bl1, t, BF); brel1h[t] = f2bf(ldf(P.br1, t, BF)); }
  __syncthreads();   // B0

  // ---- P3: adjacency nibble atomics (fire-and-forget) ----
  #pragma unroll
  for (int e = 0; e < 8; ++e) {
    unsigned nib = (unsigned)(eu[e] * 264 + ev[e]);
    atomicAdd((unsigned int*)(smem + ((nib >> 3) << 2)), 1u << ((nib & 7u) * 4u));
  }

  // ---- P1: h0 = x @ W1 + b (MFMA) -> h0T bf16 ----
  {
    f32x4 acc[2] = {{0.f,0.f,0.f,0.f},{0.f,0.f,0.f,0.f}};
    const size_t node = (size_t)(b * 256 + mbase + lm);
    #pragma unroll
    for (int ks = 0; ks < 4; ++ks) {
      const int k0 = ks * 32 + quad * 8;
      s16x8 a;
      if (BF) {
        a = *(const s16x8*)((const unsigned short*)P.x + node * 128 + k0);
      } else {
        const float* xp = (const float*)P.x + node * 128 + k0;
        f32x4 v0 = *(const f32x4*)xp;
        f32x4 v1 = *(const f32x4*)(xp + 4);
        #pragma unroll
        for (int j = 0; j < 4; ++j) { a[j] = (short)f2bf(v0[j]); a[4 + j] = (short)f2bf(v1[j]); }
      }
      #pragma unroll
      for (int ct = 0; ct < 2; ++ct) {
        s16x8 bh = *(const s16x8*)(w1t + (ct * 16 + lm) * 136 + k0);
        acc[ct] = __builtin_amdgcn_mfma_f32_16x16x32_bf16(a, bh, acc[ct], 0, 0, 0);
      }
    }
    #pragma unroll
    for (int ct = 0; ct < 2; ++ct) {
      const int c = ct * 16 + lm;
      float bias = blin1f[c];
      #pragma unroll
      for (int r = 0; r < 4; ++r)
        h0T[c * 264 + mbase + quad * 4 + r] = f2bf(acc[ct][r] + bias);
    }
  }

  // ---- M-jobs during P1: M1 = Wrel@Wpool (hi/lo), M2 = Wroot@Wpool, bM ----
  if (wv == 2 || wv == 3) {
    const int mb = (wv - 2) * 16;
    s16x8 Ah, Al;
    #pragma unroll
    for (int j = 0; j < 8; ++j) {
      int k = quad * 8 + j;
      Ah[j] = (short)wrelTh[k * 40 + mb + lm];
      Al[j] = (short)wrelTl[k * 40 + mb + lm];
    }
    s16x8 Bh, Bl;
    ((uint2*)&Bh)[0] = *(const uint2*)(wpoolTh + lm * 36 + quad * 8);
    ((uint2*)&Bh)[1] = *(const uint2*)(wpoolTh + lm * 36 + quad * 8 + 4);
    ((uint2*)&Bl)[0] = *(const uint2*)(wpoolTl + lm * 36 + quad * 8);
    ((uint2*)&Bl)[1] = *(const uint2*)(wpoolTl + lm * 36 + quad * 8 + 4);
    f32x4 acc = {0.f, 0.f, 0.f, 0.f};
    acc = __builtin_amdgcn_mfma_f32_16x16x32_bf16(Ah, Bh, acc, 0, 0, 0);
    acc = __builtin_amdgcn_mfma_f32_16x16x32_bf16(Al, Bh, acc, 0, 0, 0);
    acc = __builtin_amdgcn_mfma_f32_16x16x32_bf16(Ah, Bl, acc, 0, 0, 0);
    #pragma unroll
    for (int r = 0; r < 4; ++r) {
      int m = mb + quad * 4 + r;
      unsigned short hi = f2bf(acc[r]);
      m1Th[lm * 36 + m] = hi;
      m1Tl[lm * 36 + m] = f2bf(acc[r] - bf2f(hi));
    }
  }
  if (wv == 4 || wv == 5) {
    const int mb = (wv - 4) * 16;
    s16x8 Ah;
    #pragma unroll
    for (int j = 0; j < 8; ++j) Ah[j] = (short)wrootT[(quad * 8 + j) * 40 + mb + lm];
    s16x8 Bh, Bl;
    ((uint2*)&Bh)[0] = *(const uint2*)(wpoolTh + lm * 36 + quad * 8);
    ((uint2*)&Bh)[1] = *(const uint2*)(wpoolTh + lm * 36 + quad * 8 + 4);
    ((uint2*)&Bl)[0] = *(const uint2*)(wpoolTl + lm * 36 + quad * 8);
    ((uint2*)&Bl)[1] = *(const uint2*)(wpoolTl + lm * 36 + quad * 8 + 4);
    f32x4 acc = {0.f, 0.f, 0.f, 0.f};
    acc = __builtin_amdgcn_mfma_f32_16x16x32_bf16(Ah, Bh, acc, 0, 0, 0);
    acc = __builtin_amdgcn_mfma_f32_16x16x32_bf16(Ah, Bl, acc, 0, 0, 0);
    #pragma unroll
    for (int r = 0; r < 4; ++r) m2Th[lm * 36 + (mb + quad * 4 + r)] = f2bf(acc[r]);
  }
  if (wv == 6 && lane < 16) {
    float acc = ldf(P.bp, lane, BF);
    #pragma unroll 8
    for (int m = 0; m < 32; ++m)
      acc += bf2f(brel1h[m]) * (bf2f(wpoolTh[lane * 36 + m]) + bf2f(wpoolTl[lane * 36 + m]));
    bMf[lane] = acc;
  }
  __syncthreads();   // B1: adj, h0T, M1/M2/bM ready

  // ---- Pz1: z = h0@Wrel (h/l), r = h0@Wroot, y = h0@M1 (h/l), hM2 = h0@M2 ----
  f32x4 racc[2] = {{0.f,0.f,0.f,0.f},{0.f,0.f,0.f,0.f}};
  f32x4 yacc = {0.f,0.f,0.f,0.f}, macc = {0.f,0.f,0.f,0.f};
  {
    s16x8 Ah;
    #pragma unroll
    for (int j = 0; j < 8; ++j) Ah[j] = (short)h0T[(quad * 8 + j) * 264 + mbase + lm];
    f32x4 zacc[2] = {{0.f,0.f,0.f,0.f},{0.f,0.f,0.f,0.f}};
    #pragma unroll
    for (int ct = 0; ct < 2; ++ct) {
      const int c = ct * 16 + lm;
      s16x8 brh = *(const s16x8*)(wrelTh + c * 40 + quad * 8);
      s16x8 brl = *(const s16x8*)(wrelTl + c * 40 + quad * 8);
      s16x8 bro = *(const s16x8*)(wrootT + c * 40 + quad * 8);
      zacc[ct] = __builtin_amdgcn_mfma_f32_16x16x32_bf16(Ah, brh, zacc[ct], 0, 0, 0);
      zacc[ct] = __builtin_amdgcn_mfma_f32_16x16x32_bf16(Ah, brl, zacc[ct], 0, 0, 0);
      racc[ct] = __builtin_amdgcn_mfma_f32_16x16x32_bf16(Ah, bro, racc[ct], 0, 0, 0);
    }
    s16x8 Bm1h, Bm1l, Bm2;
    ((uint2*)&Bm1h)[0] = *(const uint2*)(m1Th + lm * 36 + quad * 8);
    ((uint2*)&Bm1h)[1] = *(const uint2*)(m1Th + lm * 36 + quad * 8 + 4);
    ((uint2*)&Bm1l)[0] = *(const uint2*)(m1Tl + lm * 36 + quad * 8);
    ((uint2*)&Bm1l)[1] = *(const uint2*)(m1Tl + lm * 36 + quad * 8 + 4);
    ((uint2*)&Bm2)[0]  = *(const uint2*)(m2Th + lm * 36 + quad * 8);
    ((uint2*)&Bm2)[1]  = *(const uint2*)(m2Th + lm * 36 + quad * 8 + 4);
    yacc = __builtin_amdgcn_mfma_f32_16x16x32_bf16(Ah, Bm1h, yacc, 0, 0, 0);
    yacc = __builtin_amdgcn_mfma_f32_16x16x32_bf16(Ah, Bm1l, yacc, 0, 0, 0);
    macc = __builtin_amdgcn_mfma_f32_16x16x32_bf16(Ah, Bm2, macc, 0, 0, 0);
    #pragma unroll
    for (int ct = 0; ct < 2; ++ct)
      #pragma unroll
      for (int r = 0; r < 4; ++r)
        zT[(ct * 16 + lm) * 264 + mbase + quad * 4 + r] = f2bf(zacc[ct][r]);
  }
  __syncthreads();   // B2: wrelT/wrootT/h0T reads done

  // ---- Pz2: yT hi/lo out ----
  #pragma unroll
  for (int r = 0; r < 4; ++r) {
    int node = mbase + quad * 4 + r;
    unsigned short hi = f2bf(yacc[r]);
    yTh[lm * 264 + node] = hi;
    yTl[lm * 264 + node] = f2bf(yacc[r] - bf2f(hi));
  }
  __syncthreads();   // B3

  // ---- 4a: h1 = A@z + r + brel ; logits = A@y + hM2 + bM ; softmax ----
  unsigned adjw[8];
  f32x4 h1v[2], sval, sq;
  float degf;
  {
    f32x4 h1acc[2] = {{0.f,0.f,0.f,0.f},{0.f,0.f,0.f,0.f}};
    f32x4 lacc = {0.f,0.f,0.f,0.f};
    unsigned dsum = 0;
    const char* arow = smem + (mbase + lm) * 132;
    #pragma unroll
    for (int ks = 0; ks < 8; ++ks) {
      unsigned d = *(const unsigned int*)(arow + ks * 16 + quad * 4);
      adjw[ks] = d;
      unsigned v = (d & 0x0F0F0F0Fu) + ((d >> 4) & 0x0F0F0F0Fu);
      dsum += (v * 0x01010101u) >> 24;
      s16x8 af;
      #pragma unroll
      for (int j = 0; j < 8; ++j) af[j] = ftrunc_bf((float)((d >> (4 * j)) & 15u));
      const int v0 = ks * 32 + quad * 8;
      #pragma unroll
      for (int ct = 0; ct < 2; ++ct) {
        s16x8 bz = *(const s16x8*)(zT + (ct * 16 + lm) * 264 + v0);
        h1acc[ct] = __builtin_amdgcn_mfma_f32_16x16x32_bf16(af, bz, h1acc[ct], 0, 0, 0);
      }
      s16x8 byh = *(const s16x8*)(yTh + lm * 264 + v0);
      s16x8 byl = *(const s16x8*)(yTl + lm * 264 + v0);
      lacc = __builtin_amdgcn_mfma_f32_16x16x32_bf16(af, byh, lacc, 0, 0, 0);
      lacc = __builtin_amdgcn_mfma_f32_16x16x32_bf16(af, byl, lacc, 0, 0, 0);
    }
    dsum += __shfl_xor(dsum, 16, 64);
    dsum += __shfl_xor(dsum, 32, 64);
    degf = (float)dsum;   // deg[mbase + lm], valid all lanes
    #pragma unroll
    for (int ct = 0; ct < 2; ++ct) {
      float bias = bf2f(brel1h[ct * 16 + lm]);
      #pragma unroll
      for (int r = 0; r < 4; ++r) h1v[ct][r] = h1acc[ct][r] + racc[ct][r] + bias;
    }
    f32x4 lg;
    float bm = bMf[lm];
    #pragma unroll
    for (int r = 0; r < 4; ++r) lg[r] = lacc[r] + macc[r] + bm;
    f32x4 mx = lg;
    #pragma unroll
    for (int m = 1; m <= 8; m <<= 1)
      #pragma unroll
      for (int r = 0; r < 4; ++r) mx[r] = fmaxf(mx[r], __shfl_xor(mx[r], m, 64));
    #pragma unroll
    for (int r = 0; r < 4; ++r) lg[r] = __expf(lg[r] - mx[r]);
    f32x4 sm = lg;
    #pragma unroll
    for (int m = 1; m <= 8; m <<= 1)
      #pragma unroll
      for (int r = 0; r < 4; ++r) sm[r] += __shfl_xor(sm[r], m, 64);
    #pragma unroll
    for (int r = 0; r < 4; ++r) { sval[r] = lg[r] / sm[r]; sq[r] = sval[r] * sval[r]; }
    #pragma unroll
    for (int m = 1; m <= 8; m <<= 1)
      #pragma unroll
      for (int r = 0; r < 4; ++r) sq[r] += __shfl_xor(sq[r], m, 64);
    // sq[r] = ssq for node mbase + quad*4 + r (valid all lanes)
  }
  __syncthreads();   // B4: zT/yT reads done

  // ---- 4b: write h1Th, sTh/sTl ----
  #pragma unroll
  for (int ct = 0; ct < 2; ++ct)
    #pragma unroll
    for (int r = 0; r < 4; ++r)
      h1Th[(ct * 16 + lm) * 264 + mbase + quad * 4 + r] = f2bf(h1v[ct][r]);
  #pragma unroll
  for (int r = 0; r < 4; ++r) {
    int node = mbase + quad * 4 + r;
    unsigned short hi = f2bf(sval[r]);
    sTh[lm * 264 + node] = hi;
    sTl[lm * 264 + node] = f2bf(sval[r] - bf2f(hi));
  }
  __syncthreads();   // B5

  // ---- P5: tA = A@s -> taT bf16 ----
  {
    f32x4 tacc = {0.f, 0.f, 0.f, 0.f};
    #pragma unroll
    for (int ks = 0; ks < 8; ++ks) {
      unsigned d = adjw[ks];
      s16x8 af;
      #pragma unroll
      for (int j = 0; j < 8; ++j) af[j] = ftrunc_bf((float)((d >> (4 * j)) & 15u));
      const int v0 = ks * 32 + quad * 8;
      s16x8 bh = *(const s16x8*)(sTh + lm * 264 + v0);
      s16x8 bl = *(const s16x8*)(sTl + lm * 264 + v0);
      tacc = __builtin_amdgcn_mfma_f32_16x16x32_bf16(af, bh, tacc, 0, 0, 0);
      tacc = __builtin_amdgcn_mfma_f32_16x16x32_bf16(af, bl, tacc, 0, 0, 0);
    }
    #pragma unroll
    for (int r = 0; r < 4; ++r) taT[lm * 264 + mbase + quad * 4 + r] = f2bf(tacc[r]);
  }
  __syncthreads();   // B6: adjacency dead

  // ---- P6: FG weights global -> A tail + 8 MFMA reduction jobs ----
  rel2f[t] = ldf(P.wr2, t, BF);
  root2f[t] = ldf(P.wro2, t, BF);
  lin2f[t] = ldf(P.wl2, t, BF);
  if (t < 320) lin3f[t] = ldf(P.wl3, t, BF);
  if (t < 32) brel2f[t] = ldf(P.br2, t, BF);
  if (t < 32) blin2f[t] = ldf(P.bl2, t, BF);
  if (t < 10) blin3f[t] = ldf(P.bl3, t, BF);

  if (wv < 8) {
    const unsigned short *Ap, *Bp; float* dst; int W, ct = 0;
    switch (wv) {
      case 0: Ap = sTh; Bp = h1Th; dst = pbufH; W = 32; ct = 0; break;
      case 1: Ap = sTh; Bp = h1Th; dst = pbufH; W = 32; ct = 1; break;
      case 2: Ap = sTl; Bp = h1Th; dst = pbufL; W = 32; ct = 0; break;
      case 3: Ap = sTl; Bp = h1Th; dst = pbufL; W = 32; ct = 1; break;
      case 4: Ap = sTh; Bp = taT;  dst = oadjH; W = 16; break;
      case 5: Ap = sTl; Bp = taT;  dst = oadjL; W = 16; break;
      case 6: Ap = sTh; Bp = sTh;  dst = ssA;   W = 16; break;
      default: Ap = sTh; Bp = sTl; dst = ssX;   W = 16; break;
    }
    const int cidx = ct * 16 + lm;
    const unsigned short* Bb = Bp + cidx * 264;
    f32x4 acc = {0.f, 0.f, 0.f, 0.f};
    #pragma unroll
    for (int ch = 0; ch < 8; ++ch) {
      s16x8 a = *(const s16x8*)(Ap + lm * 264 + ch * 32 + quad * 8);
      s16x8 bb = *(const s16x8*)(Bb + ch * 32 + quad * 8);
      acc = __builtin_amdgcn_mfma_f32_16x16x32_bf16(a, bb, acc, 0, 0, 0);
    }
    #pragma unroll
    for (int r = 0; r < 4; ++r) dst[(quad * 4 + r) * W + cidx] = acc[r];
  }
  __syncthreads();   // B7

  // ---- combine ----
  if (t < 512) {
    pbuf[t] = pbufH[t] + pbufL[t];
  } else if (t < 768) {
    int i = t - 512; oadjb[i] = oadjH[i] + oadjL[i];
  } else {
    int i = t - 768; int k3 = i >> 4, j3 = i & 15;
    ssb[i] = ssA[i] + ssX[i] + ssX[j3 * 16 + k3];
  }
  __syncthreads();   // B8

  // ---- loss part A: per-wave butterflies ----
  {
    int l = lane & 15, src = (l >> 2) << 4;
    float q0 = __shfl(sq[0], src, 64), q1 = __shfl(sq[1], src, 64);
    float q2 = __shfl(sq[2], src, 64), q3 = __shfl(sq[3], src, 64);
    float ssel = (l & 2) ? ((l & 1) ? q3 : q2) : ((l & 1) ? q1 : q0);
    float vden = (lane < 16) ? degf * ssel : 0.f;
    float vnum = (t < 16) ? oadjb[t * 17] : 0.f;
    float vfro = (t < 256) ? ssb[t] * ssb[t] : 0.f;
    float vtr  = (t < 16) ? ssb[t * 17] : 0.f;
    #pragma unroll
    for (int o = 32; o > 0; o >>= 1) {
      vden += __shfl_xor(vden, o, 64);
      vnum += __shfl_xor(vnum, o, 64);
      vfro += __shfl_xor(vfro, o, 64);
      vtr  += __shfl_xor(vtr, o, 64);
    }
    if (lane == 0) { scr[wv] = vden; scr[16 + wv] = vnum; scr[32 + wv] = vfro; scr[48 + wv] = vtr; }
  }
  __syncthreads();   // B9

  // ---- loss part B + ddb ----
  if (t == 0) {
    float den = 0.f, num = 0.f, fro = 0.f, tr = 0.f;
    #pragma unroll
    for (int i = 0; i < 16; ++i) { den += scr[i]; num += scr[16 + i]; fro += scr[32 + i]; tr += scr[48 + i]; }
    float ssn = sqrtf(fro);
    float orth2 = 2.f - tr / (2.f * ssn);
    atomicAdd(P.ws, -(num / den) * (1.f / NB));
    atomicAdd(P.ws + 1, sqrtf(fmaxf(orth2, 0.f)) * (1.f / NB));
  }
  if (t < 16) {
    float rs = 0.f;
    #pragma unroll
    for (int j = 0; j < 16; ++j) if (j != t) rs += oadjb[t * 16 + j];
    ddb[t] = sqrtf(rs) + 1e-15f;
  }
  __syncthreads();   // B10
  if (t < 256) {
    int k = t >> 4, j = t & 15;
    float apv = (k == j) ? 0.f : oadjb[t] / (ddb[k] * ddb[j]);
    oadjb[t] = apv;
  }
  __syncthreads();   // B11

  // ---- conv2 ----
  if (t < 512) {
    int k = t >> 5, c = t & 31;
    float q = 0.f;
    #pragma unroll
    for (int j = 0; j < 16; ++j) q += oadjb[k * 16 + j] * pbuf[j * 32 + c];
    qbuf[k * 32 + c] = q;
  }
  __syncthreads();   // B12
  if (t < 512) {
    int k = t >> 5, c = t & 31;
    float s0 = 0.f;
    #pragma unroll
    for (int m = 0; m < 32; ++m)
      s0 += qbuf[k * 32 + m] * rel2f[m * 32 + c] + pbuf[k * 32 + m] * root2f[m * 32 + c];
    h2b[k * 32 + c] = s0;   // bias added in readout (16*brel2)
  }
  __syncthreads();   // B13

  // ---- wave-0 tail ----
  if (wv == 0) {
    if (lane < 32) {
      float r = 16.f * brel2f[lane];
      #pragma unroll
      for (int k = 0; k < 16; ++k) r += h2b[k * 32 + lane];
      rb[lane] = r;
    }
    if (lane < 32) {
      float y = blin2f[lane];
      #pragma unroll
      for (int m = 0; m < 32; ++m) y += rb[m] * lin2f[m * 32 + lane];
      yb[lane] = fmaxf(y, 0.f);
    }
    if (lane < 10) {
      float lg = blin3f[lane];
      #pragma unroll
      for (int m = 0; m < 32; ++m) lg += yb[m] * lin3f[m * 10 + lane];
      lgb[lane] = lg;
    }
    if (lane == 0) {
      float mx = lgb[0];
      #pragma unroll
      for (int i = 1; i < 10; ++i) mx = fmaxf(mx, lgb[i]);
      float sum = 0.f;
      #pragma unroll
      for (int i = 0; i < 10; ++i) sum += __expf(lgb[i] - mx);
      lgb[10] = mx + __logf(sum);
    }
    if (lane < 10) {
      float val = lgb[lane] - lgb[10];
      if (BF) ((unsigned short*)P.out)[b * 10 + lane] = f2bf(val);
      else    P.out[b * 10 + lane] = val;
    }
  }
}

__global__ void mincut_fin(Params P) {
  if (threadIdx.x == 0) {
    const bool BF = detect_bf16(P.wr1);
    if (BF) {
      ((unsigned short*)P.out)[5120] = f2bf(P.ws[0]);
      ((unsigned short*)P.out)[5121] = f2bf(P.ws[1]);
    } else {
      P.out[5120] = P.ws[0];
      P.out[5121] = P.ws[1];
    }
  }
}

extern "C" void kernel_launch(void* const* d_in, const int* in_sizes, int n_in,
                              void* d_out, int out_size, void* d_ws, size_t ws_size,
                              hipStream_t stream) {
  (void)in_sizes; (void)n_in; (void)out_size; (void)ws_size;
  Params P;
  P.x    = d_in[0];
  P.ei   = d_in[1];
  P.wl1  = d_in[3];
  P.bl1  = d_in[4];
  P.wr1  = d_in[5];
  P.br1  = d_in[6];
  P.wro1 = d_in[7];
  P.wp   = d_in[8];
  P.bp   = d_in[9];
  P.wr2  = d_in[10];
  P.br2  = d_in[11];
  P.wro2 = d_in[12];
  P.wl2  = d_in[13];
  P.bl2  = d_in[14];
  P.wl3  = d_in[15];
  P.bl3  = d_in[16];
  P.out  = (float*)d_out;
  P.ws   = (float*)d_ws;

  hipMemsetAsync(d_ws, 0, 2 * sizeof(float), stream);
  hipFuncSetAttribute(reinterpret_cast<const void*>(mincut_main),
                      hipFuncAttributeMaxDynamicSharedMemorySize, SMEM_TOTAL);
  hipLaunchKernelGGL(mincut_main, dim3(NB), dim3(1024), SMEM_TOTAL, stream, P);
  hipLaunchKernelGGL(mincut_fin, dim3(1), dim3(64), 0, stream, P);
}

// Round 9
// 170.019 us; speedup vs baseline: 1.2010x; 1.2010x over previous
//
#include <hip/hip_runtime.h>

#define NB 512
#define NN 256
#define EPG 8192
#define FINC 128

typedef float f32x4 __attribute__((ext_vector_type(4)));
typedef short s16x8 __attribute__((ext_vector_type(8)));

__device__ __forceinline__ float bf2f(unsigned short u) {
  union { unsigned int i; float f; } x; x.i = ((unsigned int)u) << 16; return x.f;
}
__device__ __forceinline__ unsigned short f2bf(float f) {
  union { float f; unsigned int i; } x; x.f = f;
  unsigned int r = x.i + 0x7fffu + ((x.i >> 16) & 1u);
  return (unsigned short)(r >> 16);
}
// exact for small non-negative integers
__device__ __forceinline__ short ftrunc_bf(float f) {
  union { float f; unsigned int i; } x; x.f = f;
  return (short)(x.i >> 16);
}

struct Params {
  const void* x; const void* ei;
  const void *wl1, *bl1, *wr1, *br1, *wro1, *wp, *bp;
  const void *wr2, *br2, *wro2, *wl2, *bl2, *wl3, *bl3;
  float* out; float* ws;
};

__device__ __forceinline__ bool detect_bf16(const void* p) {
  const unsigned short* pw = (const unsigned short*)p;
  int sane = 0;
  for (int i = 0; i < 64; ++i) {
    unsigned e = (pw[i] >> 7) & 0xFFu;
    sane += (e > 96u && e < 132u) ? 1 : 0;
  }
  return sane >= 56;
}
__device__ __forceinline__ bool detect_i64(const void* p) {
  const int* pi = (const int*)p + EPG;
  int ok = 0;
  for (int i = 0; i < 32; ++i) ok += (pi[i] >= 256 && pi[i] < 512) ? 1 : 0;
  return ok < 24;
}
__device__ __forceinline__ float ldf(const void* p, int i, bool bf) {
  return bf ? bf2f(((const unsigned short*)p)[i]) : ((const float*)p)[i];
}

// ---- LDS (81920 B total => 2 blocks/CU) ----
// A [0,33792):     adj u4 [256 rows][132 B]; after P5: tail bufs + FG + jobs
// B [33792,50688): h0T bf16 [32][264] (P1->Pz1); yTl [16][264] (Pz2->4a);
//                  h1Th [32][264] (4b->P6)
// C [50688,67584): W1T bf16 [32][136] (P0->P1); zT [32][264] (Pz1->4a);
//                  sTh/sTl [16][264] x2 (4b->P6)
// D [67584,76032): wrelTh/l + wrootT [32][40] + blin1f (P0->Pz1);
//                  yTh [16][264] (Pz2->4a); taT [16][264] (P5->P6)
// E [76032,81920): wpoolTh/l, m1Th/l, m2Th [16][36]; bMf; brel1h (m1Tl hosts
//                  the den-loss scratch after Pz1)
#define SMEM_TOTAL 81920

__global__ __launch_bounds__(1024, 8) void mincut_main(Params P) {
  extern __shared__ char smem[];
  const int t = threadIdx.x;
  const int b = blockIdx.x;

  const bool BF  = detect_bf16(P.wr1);
  const bool I64 = detect_i64(P.ei);

  // A tail
  float* pbuf   = (float*)(smem + 0);
  float* oadjb  = (float*)(smem + 2048);
  float* ssb    = (float*)(smem + 3072);
  float* qbuf   = (float*)(smem + 4096);
  float* ddb    = (float*)(smem + 6144);
  float* h2b    = (float*)(smem + 6208);
  float* rb     = (float*)(smem + 8256);
  float* yb     = (float*)(smem + 8384);
  float* lgb    = (float*)(smem + 8512);
  float* scr    = (float*)(smem + 8704);    // 64 f
  float* rel2f  = (float*)(smem + 9216);
  float* root2f = (float*)(smem + 13312);
  float* lin2f  = (float*)(smem + 17408);
  float* lin3f  = (float*)(smem + 21504);
  float* brel2f = (float*)(smem + 22784);
  float* blin2f = (float*)(smem + 22912);
  float* blin3f = (float*)(smem + 23040);
  float* pbufH  = (float*)(smem + 24576);
  float* pbufL  = (float*)(smem + 26624);
  float* oadjH  = (float*)(smem + 28672);
  float* oadjL  = (float*)(smem + 29696);
  float* ssA    = (float*)(smem + 30720);
  float* ssX    = (float*)(smem + 31744);
  // B
  unsigned short* h0T  = (unsigned short*)(smem + 33792);
  unsigned short* yTl  = (unsigned short*)(smem + 33792);
  unsigned short* h1Th = (unsigned short*)(smem + 33792);
  // C
  unsigned short* w1t  = (unsigned short*)(smem + 50688);
  unsigned short* zT   = (unsigned short*)(smem + 50688);
  unsigned short* sTh  = (unsigned short*)(smem + 50688);
  unsigned short* sTl  = (unsigned short*)(smem + 59136);
  // D
  unsigned short* wrelTh = (unsigned short*)(smem + 67584);
  unsigned short* wrelTl = (unsigned short*)(smem + 70144);
  unsigned short* wrootT = (unsigned short*)(smem + 72704);
  float* blin1f = (float*)(smem + 75264);   // 32 f (dead after P1)
  unsigned short* yTh = (unsigned short*)(smem + 67584);
  unsigned short* taT = (unsigned short*)(smem + 67584);
  // E
  unsigned short* wpoolTh = (unsigned short*)(smem + 76032); // [16][36]
  unsigned short* wpoolTl = (unsigned short*)(smem + 77184);
  unsigned short* m1Th    = (unsigned short*)(smem + 78336);
  unsigned short* m1Tl    = (unsigned short*)(smem + 79488);
  float*          scrE    = (float*)(smem + 79488);          // den scratch (post-Pz1)
  unsigned short* m2Th    = (unsigned short*)(smem + 80640);
  float*          bMf     = (float*)(smem + 81792);          // 16 f
  unsigned short* brel1h  = (unsigned short*)(smem + 81856); // 32 bf16

  const int wv = t >> 6, lane = t & 63;
  const int lm = lane & 15, quad = lane >> 4;
  const int mbase = wv * 16;

  // ---- P0: zero adj (u4) + stage W1T, wrelT h/l, wrootT, wpoolT h/l, biases ----
  {
    uint4 z = {0u, 0u, 0u, 0u};
    for (int i = t; i < 2112; i += 1024) ((uint4*)smem)[i] = z;
  }
  for (int e = t; e < 4096; e += 1024) {
    int k = e >> 5, c = e & 31;
    w1t[c * 136 + k] = f2bf(ldf(P.wl1, e, BF));
  }
  {
    int k = t >> 5, c = t & 31;
    float wr = ldf(P.wr1, t, BF);
    unsigned short hi = f2bf(wr);
    wrelTh[c * 40 + k] = hi;
    wrelTl[c * 40 + k] = f2bf(wr - bf2f(hi));
    wrootT[c * 40 + k] = f2bf(ldf(P.wro1, t, BF));
  }
  if (t < 512) {
    int m = t >> 4, c = t & 15;
    float w = ldf(P.wp, t, BF);
    unsigned short hi = f2bf(w);
    wpoolTh[c * 36 + m] = hi;
    wpoolTl[c * 36 + m] = f2bf(w - bf2f(hi));
  }
  if (t < 32) { blin1f[t] = ldf(P.bl1, t, BF); brel1h[t] = f2bf(ldf(P.br1, t, BF)); }
  __syncthreads();   // B0

  // ---- P3: adjacency nibble atomics, inline loads (short-lived regs) ----
  if (I64) {
    const uint4* s4 = (const uint4*)((const long long*)P.ei + (size_t)b * EPG) + t * 4;
    const uint4* d4 = (const uint4*)((const long long*)P.ei + (size_t)NB * EPG + (size_t)b * EPG) + t * 4;
    #pragma unroll
    for (int i = 0; i < 4; ++i) {
      uint4 a = s4[i], c = d4[i];
      unsigned n0 = (a.x & 255u) * 264u + (c.x & 255u);
      unsigned n1 = (a.z & 255u) * 264u + (c.z & 255u);
      atomicAdd((unsigned int*)(smem + ((n0 >> 3) << 2)), 1u << ((n0 & 7u) * 4u));
      atomicAdd((unsigned int*)(smem + ((n1 >> 3) << 2)), 1u << ((n1 & 7u) * 4u));
    }
  } else {
    const uint4* s4 = (const uint4*)((const int*)P.ei + (size_t)b * EPG) + t * 2;
    const uint4* d4 = (const uint4*)((const int*)P.ei + (size_t)NB * EPG + (size_t)b * EPG) + t * 2;
    #pragma unroll
    for (int i = 0; i < 2; ++i) {
      uint4 a = s4[i], c = d4[i];
      unsigned n0 = (a.x & 255u) * 264u + (c.x & 255u);
      unsigned n1 = (a.y & 255u) * 264u + (c.y & 255u);
      unsigned n2 = (a.z & 255u) * 264u + (c.z & 255u);
      unsigned n3 = (a.w & 255u) * 264u + (c.w & 255u);
      atomicAdd((unsigned int*)(smem + ((n0 >> 3) << 2)), 1u << ((n0 & 7u) * 4u));
      atomicAdd((unsigned int*)(smem + ((n1 >> 3) << 2)), 1u << ((n1 & 7u) * 4u));
      atomicAdd((unsigned int*)(smem + ((n2 >> 3) << 2)), 1u << ((n2 & 7u) * 4u));
      atomicAdd((unsigned int*)(smem + ((n3 >> 3) << 2)), 1u << ((n3 & 7u) * 4u));
    }
  }

  // ---- P1: h0 = x @ W1 + b (MFMA) -> h0T bf16 ----
  {
    f32x4 acc[2] = {{0.f,0.f,0.f,0.f},{0.f,0.f,0.f,0.f}};
    const size_t node = (size_t)(b * 256 + mbase + lm);
    #pragma unroll
    for (int ks = 0; ks < 4; ++ks) {
      const int k0 = ks * 32 + quad * 8;
      s16x8 a;
      if (BF) {
        a = *(const s16x8*)((const unsigned short*)P.x + node * 128 + k0);
      } else {
        const float* xp = (const float*)P.x + node * 128 + k0;
        f32x4 v0 = *(const f32x4*)xp;
        f32x4 v1 = *(const f32x4*)(xp + 4);
        #pragma unroll
        for (int j = 0; j < 4; ++j) { a[j] = (short)f2bf(v0[j]); a[4 + j] = (short)f2bf(v1[j]); }
      }
      #pragma unroll
      for (int ct = 0; ct < 2; ++ct) {
        s16x8 bh = *(const s16x8*)(w1t + (ct * 16 + lm) * 136 + k0);
        acc[ct] = __builtin_amdgcn_mfma_f32_16x16x32_bf16(a, bh, acc[ct], 0, 0, 0);
      }
    }
    #pragma unroll
    for (int ct = 0; ct < 2; ++ct) {
      const int c = ct * 16 + lm;
      float bias = blin1f[c];
      #pragma unroll
      for (int r = 0; r < 4; ++r)
        h0T[c * 264 + mbase + quad * 4 + r] = f2bf(acc[ct][r] + bias);
    }
  }

  // ---- M-jobs during P1: M1 = Wrel@Wpool (hi/lo), M2 = Wroot@Wpool, bM ----
  if (wv == 2 || wv == 3) {
    const int mb = (wv - 2) * 16;
    s16x8 Ah, Al;
    #pragma unroll
    for (int j = 0; j < 8; ++j) {
      int k = quad * 8 + j;
      Ah[j] = (short)wrelTh[k * 40 + mb + lm];
      Al[j] = (short)wrelTl[k * 40 + mb + lm];
    }
    s16x8 Bh, Bl;
    ((uint2*)&Bh)[0] = *(const uint2*)(wpoolTh + lm * 36 + quad * 8);
    ((uint2*)&Bh)[1] = *(const uint2*)(wpoolTh + lm * 36 + quad * 8 + 4);
    ((uint2*)&Bl)[0] = *(const uint2*)(wpoolTl + lm * 36 + quad * 8);
    ((uint2*)&Bl)[1] = *(const uint2*)(wpoolTl + lm * 36 + quad * 8 + 4);
    f32x4 acc = {0.f, 0.f, 0.f, 0.f};
    acc = __builtin_amdgcn_mfma_f32_16x16x32_bf16(Ah, Bh, acc, 0, 0, 0);
    acc = __builtin_amdgcn_mfma_f32_16x16x32_bf16(Al, Bh, acc, 0, 0, 0);
    acc = __builtin_amdgcn_mfma_f32_16x16x32_bf16(Ah, Bl, acc, 0, 0, 0);
    #pragma unroll
    for (int r = 0; r < 4; ++r) {
      int m = mb + quad * 4 + r;
      unsigned short hi = f2bf(acc[r]);
      m1Th[lm * 36 + m] = hi;
      m1Tl[lm * 36 + m] = f2bf(acc[r] - bf2f(hi));
    }
  }
  if (wv == 4 || wv == 5) {
    const int mb = (wv - 4) * 16;
    s16x8 Ah;
    #pragma unroll
    for (int j = 0; j < 8; ++j) Ah[j] = (short)wrootT[(quad * 8 + j) * 40 + mb + lm];
    s16x8 Bh, Bl;
    ((uint2*)&Bh)[0] = *(const uint2*)(wpoolTh + lm * 36 + quad * 8);
    ((uint2*)&Bh)[1] = *(const uint2*)(wpoolTh + lm * 36 + quad * 8 + 4);
    ((uint2*)&Bl)[0] = *(const uint2*)(wpoolTl + lm * 36 + quad * 8);
    ((uint2*)&Bl)[1] = *(const uint2*)(wpoolTl + lm * 36 + quad * 8 + 4);
    f32x4 acc = {0.f, 0.f, 0.f, 0.f};
    acc = __builtin_amdgcn_mfma_f32_16x16x32_bf16(Ah, Bh, acc, 0, 0, 0);
    acc = __builtin_amdgcn_mfma_f32_16x16x32_bf16(Ah, Bl, acc, 0, 0, 0);
    #pragma unroll
    for (int r = 0; r < 4; ++r) m2Th[lm * 36 + (mb + quad * 4 + r)] = f2bf(acc[r]);
  }
  if (wv == 6 && lane < 16) {
    float acc = ldf(P.bp, lane, BF);
    #pragma unroll 8
    for (int m = 0; m < 32; ++m)
      acc += bf2f(brel1h[m]) * (bf2f(wpoolTh[lane * 36 + m]) + bf2f(wpoolTl[lane * 36 + m]));
    bMf[lane] = acc;
  }
  __syncthreads();   // B1: adj, h0T, M1/M2/bM ready

  // ---- Pz1: z = h0@Wrel (h/l), r = h0@Wroot, y = h0@M1 (h/l), hM2 = h0@M2 ----
  f32x4 racc[2] = {{0.f,0.f,0.f,0.f},{0.f,0.f,0.f,0.f}};
  f32x4 yacc = {0.f,0.f,0.f,0.f}, macc = {0.f,0.f,0.f,0.f};
  {
    s16x8 Ah;
    #pragma unroll
    for (int j = 0; j < 8; ++j) Ah[j] = (short)h0T[(quad * 8 + j) * 264 + mbase + lm];
    f32x4 zacc[2] = {{0.f,0.f,0.f,0.f},{0.f,0.f,0.f,0.f}};
    #pragma unroll
    for (int ct = 0; ct < 2; ++ct) {
      const int c = ct * 16 + lm;
      s16x8 brh = *(const s16x8*)(wrelTh + c * 40 + quad * 8);
      s16x8 brl = *(const s16x8*)(wrelTl + c * 40 + quad * 8);
      s16x8 bro = *(const s16x8*)(wrootT + c * 40 + quad * 8);
      zacc[ct] = __builtin_amdgcn_mfma_f32_16x16x32_bf16(Ah, brh, zacc[ct], 0, 0, 0);
      zacc[ct] = __builtin_amdgcn_mfma_f32_16x16x32_bf16(Ah, brl, zacc[ct], 0, 0, 0);
      racc[ct] = __builtin_amdgcn_mfma_f32_16x16x32_bf16(Ah, bro, racc[ct], 0, 0, 0);
    }
    s16x8 Bm1h, Bm1l, Bm2;
    ((uint2*)&Bm1h)[0] = *(const uint2*)(m1Th + lm * 36 + quad * 8);
    ((uint2*)&Bm1h)[1] = *(const uint2*)(m1Th + lm * 36 + quad * 8 + 4);
    ((uint2*)&Bm1l)[0] = *(const uint2*)(m1Tl + lm * 36 + quad * 8);
    ((uint2*)&Bm1l)[1] = *(const uint2*)(m1Tl + lm * 36 + quad * 8 + 4);
    ((uint2*)&Bm2)[0]  = *(const uint2*)(m2Th + lm * 36 + quad * 8);
    ((uint2*)&Bm2)[1]  = *(const uint2*)(m2Th + lm * 36 + quad * 8 + 4);
    yacc = __builtin_amdgcn_mfma_f32_16x16x32_bf16(Ah, Bm1h, yacc, 0, 0, 0);
    yacc = __builtin_amdgcn_mfma_f32_16x16x32_bf16(Ah, Bm1l, yacc, 0, 0, 0);
    macc = __builtin_amdgcn_mfma_f32_16x16x32_bf16(Ah, Bm2, macc, 0, 0, 0);
    #pragma unroll
    for (int ct = 0; ct < 2; ++ct)
      #pragma unroll
      for (int r = 0; r < 4; ++r)
        zT[(ct * 16 + lm) * 264 + mbase + quad * 4 + r] = f2bf(zacc[ct][r]);
  }
  __syncthreads();   // B2: wrelT/wrootT/h0T/m1/m2 reads done

  // ---- Pz2: yT hi/lo out ----
  #pragma unroll
  for (int r = 0; r < 4; ++r) {
    int node = mbase + quad * 4 + r;
    unsigned short hi = f2bf(yacc[r]);
    yTh[lm * 264 + node] = hi;
    yTl[lm * 264 + node] = f2bf(yacc[r] - bf2f(hi));
  }
  __syncthreads();   // B3

  // ---- 4a: h1 = A@z + r + brel ; logits = A@y + hM2 + bM ; softmax; den ----
  f32x4 h1v[2], sval;
  {
    f32x4 h1acc[2] = { racc[0], racc[1] };   // C-operand carries Pz1 result
    f32x4 lacc = macc;
    unsigned dsum = 0;
    const char* arow = smem + (mbase + lm) * 132;
    #pragma unroll
    for (int ks = 0; ks < 8; ++ks) {
      unsigned d = *(const unsigned int*)(arow + ks * 16 + quad * 4);
      unsigned v = (d & 0x0F0F0F0Fu) + ((d >> 4) & 0x0F0F0F0Fu);
      dsum += (v * 0x01010101u) >> 24;
      s16x8 af;
      #pragma unroll
      for (int j = 0; j < 8; ++j) af[j] = ftrunc_bf((float)((d >> (4 * j)) & 15u));
      const int v0 = ks * 32 + quad * 8;
      #pragma unroll
      for (int ct = 0; ct < 2; ++ct) {
        s16x8 bz = *(const s16x8*)(zT + (ct * 16 + lm) * 264 + v0);
        h1acc[ct] = __builtin_amdgcn_mfma_f32_16x16x32_bf16(af, bz, h1acc[ct], 0, 0, 0);
      }
      s16x8 byh = *(const s16x8*)(yTh + lm * 264 + v0);
      s16x8 byl = *(const s16x8*)(yTl + lm * 264 + v0);
      lacc = __builtin_amdgcn_mfma_f32_16x16x32_bf16(af, byh, lacc, 0, 0, 0);
      lacc = __builtin_amdgcn_mfma_f32_16x16x32_bf16(af, byl, lacc, 0, 0, 0);
    }
    dsum += __shfl_xor(dsum, 16, 64);
    dsum += __shfl_xor(dsum, 32, 64);
    float degf = (float)dsum;   // deg of node mbase+lm
    #pragma unroll
    for (int ct = 0; ct < 2; ++ct) {
      float bias = bf2f(brel1h[ct * 16 + lm]);
      #pragma unroll
      for (int r = 0; r < 4; ++r) h1v[ct][r] = h1acc[ct][r] + bias;
    }
    f32x4 lg;
    float bm = bMf[lm];
    #pragma unroll
    for (int r = 0; r < 4; ++r) lg[r] = lacc[r] + bm;
    f32x4 mx = lg;
    #pragma unroll
    for (int m = 1; m <= 8; m <<= 1)
      #pragma unroll
      for (int r = 0; r < 4; ++r) mx[r] = fmaxf(mx[r], __shfl_xor(mx[r], m, 64));
    #pragma unroll
    for (int r = 0; r < 4; ++r) lg[r] = __expf(lg[r] - mx[r]);
    f32x4 sm = lg;
    #pragma unroll
    for (int m = 1; m <= 8; m <<= 1)
      #pragma unroll
      for (int r = 0; r < 4; ++r) sm[r] += __shfl_xor(sm[r], m, 64);
    f32x4 sq;
    #pragma unroll
    for (int r = 0; r < 4; ++r) { sval[r] = lg[r] / sm[r]; sq[r] = sval[r] * sval[r]; }
    #pragma unroll
    for (int m = 1; m <= 8; m <<= 1)
      #pragma unroll
      for (int r = 0; r < 4; ++r) sq[r] += __shfl_xor(sq[r], m, 64);
    // den partial: node mbase+l (l<16): ssq from quad l>>2, slot l&3
    {
      int l = lane & 15, src = (l >> 2) << 4;
      float q0 = __shfl(sq[0], src, 64), q1 = __shfl(sq[1], src, 64);
      float q2 = __shfl(sq[2], src, 64), q3 = __shfl(sq[3], src, 64);
      float ssel = (l & 2) ? ((l & 1) ? q3 : q2) : ((l & 1) ? q1 : q0);
      float vden = (lane < 16) ? degf * ssel : 0.f;
      #pragma unroll
      for (int o = 32; o > 0; o >>= 1) vden += __shfl_xor(vden, o, 64);
      if (lane == 0) scrE[wv] = vden;   // m1Tl region, dead after Pz1
    }
  }
  __syncthreads();   // B4: zT/yT reads done

  // ---- 4b: write h1Th, sTh/sTl ----
  #pragma unroll
  for (int ct = 0; ct < 2; ++ct)
    #pragma unroll
    for (int r = 0; r < 4; ++r)
      h1Th[(ct * 16 + lm) * 264 + mbase + quad * 4 + r] = f2bf(h1v[ct][r]);
  #pragma unroll
  for (int r = 0; r < 4; ++r) {
    int node = mbase + quad * 4 + r;
    unsigned short hi = f2bf(sval[r]);
    sTh[lm * 264 + node] = hi;
    sTl[lm * 264 + node] = f2bf(sval[r] - bf2f(hi));
  }
  __syncthreads();   // B5

  // ---- P5: tA = A@s -> taT bf16 (adj re-read from LDS) ----
  {
    f32x4 tacc = {0.f, 0.f, 0.f, 0.f};
    const char* arow = smem + (mbase + lm) * 132;
    #pragma unroll
    for (int ks = 0; ks < 8; ++ks) {
      unsigned d = *(const unsigned int*)(arow + ks * 16 + quad * 4);
      s16x8 af;
      #pragma unroll
      for (int j = 0; j < 8; ++j) af[j] = ftrunc_bf((float)((d >> (4 * j)) & 15u));
      const int v0 = ks * 32 + quad * 8;
      s16x8 bh = *(const s16x8*)(sTh + lm * 264 + v0);
      s16x8 bl = *(const s16x8*)(sTl + lm * 264 + v0);
      tacc = __builtin_amdgcn_mfma_f32_16x16x32_bf16(af, bh, tacc, 0, 0, 0);
      tacc = __builtin_amdgcn_mfma_f32_16x16x32_bf16(af, bl, tacc, 0, 0, 0);
    }
    #pragma unroll
    for (int r = 0; r < 4; ++r) taT[lm * 264 + mbase + quad * 4 + r] = f2bf(tacc[r]);
  }
  __syncthreads();   // B6: adjacency dead

  // ---- P6: FG weights global -> A tail + 8 MFMA reduction jobs ----
  rel2f[t] = ldf(P.wr2, t, BF);
  root2f[t] = ldf(P.wro2, t, BF);
  lin2f[t] = ldf(P.wl2, t, BF);
  if (t < 320) lin3f[t] = ldf(P.wl3, t, BF);
  if (t < 32) brel2f[t] = ldf(P.br2, t, BF);
  if (t < 32) blin2f[t] = ldf(P.bl2, t, BF);
  if (t < 10) blin3f[t] = ldf(P.bl3, t, BF);

  if (wv < 8) {
    const unsigned short *Ap, *Bp; float* dst; int W, ct = 0;
    switch (wv) {
      case 0: Ap = sTh; Bp = h1Th; dst = pbufH; W = 32; ct = 0; break;
      case 1: Ap = sTh; Bp = h1Th; dst = pbufH; W = 32; ct = 1; break;
      case 2: Ap = sTl; Bp = h1Th; dst = pbufL; W = 32; ct = 0; break;
      case 3: Ap = sTl; Bp = h1Th; dst = pbufL; W = 32; ct = 1; break;
      case 4: Ap = sTh; Bp = taT;  dst = oadjH; W = 16; break;
      case 5: Ap = sTl; Bp = taT;  dst = oadjL; W = 16; break;
      case 6: Ap = sTh; Bp = sTh;  dst = ssA;   W = 16; break;
      default: Ap = sTh; Bp = sTl; dst = ssX;   W = 16; break;
    }
    const int cidx = ct * 16 + lm;
    const unsigned short* Bb = Bp + cidx * 264;
    f32x4 acc = {0.f, 0.f, 0.f, 0.f};
    #pragma unroll
    for (int ch = 0; ch < 8; ++ch) {
      s16x8 a = *(const s16x8*)(Ap + lm * 264 + ch * 32 + quad * 8);
      s16x8 bb = *(const s16x8*)(Bb + ch * 32 + quad * 8);
      acc = __builtin_amdgcn_mfma_f32_16x16x32_bf16(a, bb, acc, 0, 0, 0);
    }
    #pragma unroll
    for (int r = 0; r < 4; ++r) dst[(quad * 4 + r) * W + cidx] = acc[r];
  }
  __syncthreads();   // B7

  // ---- combine ----
  if (t < 512) {
    pbuf[t] = pbufH[t] + pbufL[t];
  } else if (t < 768) {
    int i = t - 512; oadjb[i] = oadjH[i] + oadjL[i];
  } else {
    int i = t - 768; int k3 = i >> 4, j3 = i & 15;
    ssb[i] = ssA[i] + ssX[i] + ssX[j3 * 16 + k3];
  }
  __syncthreads();   // B8

  // ---- loss part A: num/fro/tr butterflies ----
  {
    float vnum = (t < 16) ? oadjb[t * 17] : 0.f;
    float vfro = (t < 256) ? ssb[t] * ssb[t] : 0.f;
    float vtr  = (t < 16) ? ssb[t * 17] : 0.f;
    #pragma unroll
    for (int o = 32; o > 0; o >>= 1) {
      vnum += __shfl_xor(vnum, o, 64);
      vfro += __shfl_xor(vfro, o, 64);
      vtr  += __shfl_xor(vtr, o, 64);
    }
    if (lane == 0) { scr[16 + wv] = vnum; scr[32 + wv] = vfro; scr[48 + wv] = vtr; }
  }
  __syncthreads();   // B9

  // ---- loss part B + ddb ----
  if (t == 0) {
    float den = 0.f, num = 0.f, fro = 0.f, tr = 0.f;
    #pragma unroll
    for (int i = 0; i < 16; ++i) { den += scrE[i]; num += scr[16 + i]; fro += scr[32 + i]; tr += scr[48 + i]; }
    float ssn = sqrtf(fro);
    float orth2 = 2.f - tr / (2.f * ssn);
    atomicAdd(P.ws, -(num / den) * (1.f / NB));
    atomicAdd(P.ws + 1, sqrtf(fmaxf(orth2, 0.f)) * (1.f / NB));
  }
  if (t < 16) {
    float rs = 0.f;
    #pragma unroll
    for (int j = 0; j < 16; ++j) if (j != t) rs += oadjb[t * 16 + j];
    ddb[t] = sqrtf(rs) + 1e-15f;
  }
  __syncthreads();   // B10
  if (t < 256) {
    int k = t >> 4, j = t & 15;
    float apv = (k == j) ? 0.f : oadjb[t] / (ddb[k] * ddb[j]);
    oadjb[t] = apv;
  }
  __syncthreads();   // B11

  // ---- conv2 ----
  if (t < 512) {
    int k = t >> 5, c = t & 31;
    float q = 0.f;
    #pragma unroll
    for (int j = 0; j < 16; ++j) q += oadjb[k * 16 + j] * pbuf[j * 32 + c];
    qbuf[k * 32 + c] = q;
  }
  __syncthreads();   // B12
  if (t < 512) {
    int k = t >> 5, c = t & 31;
    float s0 = 0.f;
    #pragma unroll
    for (int m = 0; m < 32; ++m)
      s0 += qbuf[k * 32 + m] * rel2f[m * 32 + c] + pbuf[k * 32 + m] * root2f[m * 32 + c];
    h2b[k * 32 + c] = s0;   // bias added in readout (16*brel2)
  }
  __syncthreads();   // B13

  // ---- wave-0 tail ----
  if (wv == 0) {
    if (lane < 32) {
      float r = 16.f * brel2f[lane];
      #pragma unroll
      for (int k = 0; k < 16; ++k) r += h2b[k * 32 + lane];
      rb[lane] = r;
    }
    if (lane < 32) {
      float y = blin2f[lane];
      #pragma unroll
      for (int m = 0; m < 32; ++m) y += rb[m] * lin2f[m * 32 + lane];
      yb[lane] = fmaxf(y, 0.f);
    }
    if (lane < 10) {
      float lg = blin3f[lane];
      #pragma unroll
      for (int m = 0; m < 32; ++m) lg += yb[m] * lin3f[m * 10 + lane];
      lgb[lane] = lg;
    }
    if (lane == 0) {
      float mx = lgb[0];
      #pragma unroll
      for (int i = 1; i < 10; ++i) mx = fmaxf(mx, lgb[i]);
      float sum = 0.f;
      #pragma unroll
      for (int i = 0; i < 10; ++i) sum += __expf(lgb[i] - mx);
      lgb[10] = mx + __logf(sum);
    }
    if (lane < 10) {
      float val = lgb[lane] - lgb[10];
      if (BF) ((unsigned short*)P.out)[b * 10 + lane] = f2bf(val);
      else    P.out[b * 10 + lane] = val;
    }
  }
}

__global__ void mincut_fin(Params P) {
  if (threadIdx.x == 0) {
    const bool BF = detect_bf16(P.wr1);
    if (BF) {
      ((unsigned short*)P.out)[5120] = f2bf(P.ws[0]);
      ((unsigned short*)P.out)[5121] = f2bf(P.ws[1]);
    } else {
      P.out[5120] = P.ws[0];
      P.out[5121] = P.ws[1];
    }
  }
}

extern "C" void kernel_launch(void* const* d_in, const int* in_sizes, int n_in,
                              void* d_out, int out_size, void* d_ws, size_t ws_size,
                              hipStream_t stream) {
  (void)in_sizes; (void)n_in; (void)out_size; (void)ws_size;
  Params P;
  P.x    = d_in[0];
  P.ei   = d_in[1];
  P.wl1  = d_in[3];
  P.bl1  = d_in[4];
  P.wr1  = d_in[5];
  P.br1  = d_in[6];
  P.wro1 = d_in[7];
  P.wp   = d_in[8];
  P.bp   = d_in[9];
  P.wr2  = d_in[10];
  P.br2  = d_in[11];
  P.wro2 = d_in[12];
  P.wl2  = d_in[13];
  P.bl2  = d_in[14];
  P.wl3  = d_in[15];
  P.bl3  = d_in[16];
  P.out  = (float*)d_out;
  P.ws   = (float*)d_ws;

  hipMemsetAsync(d_ws, 0, 2 * sizeof(float), stream);
  hipFuncSetAttribute(reinterpret_cast<const void*>(mincut_main),
                      hipFuncAttributeMaxDynamicSharedMemorySize, SMEM_TOTAL);
  hipLaunchKernelGGL(mincut_main, dim3(NB), dim3(1024), SMEM_TOTAL, stream, P);
  hipLaunchKernelGGL(mincut_fin, dim3(1), dim3(64), 0, stream, P);
}